// Round 8
// baseline (81.920 us; speedup 1.0000x reference)
//
#include <hip/hip_runtime.h>

// TorchVQC: 8-qubit statevector, B=16384, D=256, fp32 complex.
// R8 layout: 2 batch elements per wave (32 lanes each), 8 amplitudes per lane.
// Stored index s = (j<<5) | lane32 : lane32 = s[4:0], register j = s[7:5].
// CNOTs folded away via GF(2) relabeling; 8-bit v/u masks verified R2-R7,
// re-split here as VREG=v>>5, VLANE=v&31 (same for u).
// SU(2) sign-folding (R7, verified): gate = g00r/giP/brP/g01i only.
// Cross-lane via ds_swizzle BitMode (xor within 32-lane half = exactly one
// batch group), no address VGPR, single DS op.
// Gate matrices computed per-block by lanes 0..15 into LDS (prep launch gone).
// R5 lesson: op_sel on v_pk_*_f32 not honored on gfx950 — not used.

using f2 = __attribute__((ext_vector_type(2))) float;  // (re, im)

template<int M>
__device__ __forceinline__ float swzf(float v) {
    return __int_as_float(__builtin_amdgcn_ds_swizzle(__float_as_int(v),
                                                      (M << 10) | 0x1F));
}
template<int M>
__device__ __forceinline__ f2 swz(f2 v) {
    f2 r; r.x = swzf<M>(v.x); r.y = swzf<M>(v.y); return r;
}

__device__ __forceinline__ f2 cmul2(f2 w, f2 z) {
    f2 r;
    r.x = w.x * z.x - w.y * z.y;
    r.y = w.x * z.y + w.y * z.x;
    return r;
}
__device__ __forceinline__ f2 cmadd(f2 acc, f2 w, f2 z) {
    acc.x += w.x * z.x - w.y * z.y;
    acc.y += w.x * z.y + w.y * z.x;
    return acc;
}
__device__ __forceinline__ float uxor(float f, unsigned u) {
    return __uint_as_float(__float_as_uint(f) ^ u);
}

// selected encoding-column entry: hi ? (s*cp, s*sp) : (c*cp, -c*sp)
__device__ __forceinline__ f2 enc_sel(float t, float p, bool hi) {
    float s_, c_, sp_, cp_;
    __sincosf(t * 0.5f, &s_, &c_);
    __sincosf(p * 0.5f, &sp_, &cp_);
    const float m = hi ? s_ : c_;
    f2 r; r.x = m * cp_; r.y = hi ? m * sp_ : -m * sp_;
    return r;
}

// SU(2) gate under relabeling (semantics identical to R7's gateU, verified):
// giP = g00i^lanesign, brP = g01r^lanesign; per amp j the compile-time sign
// sigma = (-1)^par(j&UREG) is folded into fma neg modifiers.
template<int VREG, int VLANE, int UREG>
__device__ __forceinline__ void gateU(f2 (&s)[8],
                                      float g00r, float giP, float brP, float g01i)
{
    if constexpr (VLANE == 0) {
        constexpr int pivot = VREG & (-VREG);
        #pragma unroll
        for (int j = 0; j < 8; ++j) {
            if ((j & pivot) != 0) continue;
            const int j2 = j ^ VREG;
            const f2 x = s[j], y = s[j2];
            {
                const bool n = (__builtin_popcount(j & UREG) & 1) != 0;
                const float gi = n ? -giP : giP, br = n ? -brP : brP;
                s[j].x = fmaf(-g01i, y.y, fmaf(br, y.x, fmaf(-gi, x.y, g00r * x.x)));
                s[j].y = fmaf( g01i, y.x, fmaf(br, y.y, fmaf( gi, x.x, g00r * x.y)));
            }
            {
                const bool n = (__builtin_popcount(j2 & UREG) & 1) != 0;
                const float gi = n ? -giP : giP, br = n ? -brP : brP;
                s[j2].x = fmaf(-g01i, x.y, fmaf(br, x.x, fmaf(-gi, y.y, g00r * y.x)));
                s[j2].y = fmaf( g01i, x.x, fmaf(br, x.y, fmaf( gi, y.x, g00r * y.y)));
            }
        }
    } else if constexpr (VREG == 0) {
        #pragma unroll
        for (int j = 0; j < 8; ++j) {
            const f2 w = swz<VLANE>(s[j]);
            const f2 x = s[j];
            const bool n = (__builtin_popcount(j & UREG) & 1) != 0;
            const float gi = n ? -giP : giP, br = n ? -brP : brP;
            s[j].x = fmaf(-g01i, w.y, fmaf(br, w.x, fmaf(-gi, x.y, g00r * x.x)));
            s[j].y = fmaf( g01i, w.x, fmaf(br, w.y, fmaf( gi, x.x, g00r * x.y)));
        }
    } else {
        constexpr int pivot = VREG & (-VREG);
        #pragma unroll
        for (int j = 0; j < 8; ++j) {
            if ((j & pivot) != 0) continue;
            const int j2 = j ^ VREG;
            const f2 p1 = swz<VLANE>(s[j2]);
            const f2 p2 = swz<VLANE>(s[j]);
            const f2 x = s[j], y = s[j2];
            {
                const bool n = (__builtin_popcount(j & UREG) & 1) != 0;
                const float gi = n ? -giP : giP, br = n ? -brP : brP;
                s[j].x = fmaf(-g01i, p1.y, fmaf(br, p1.x, fmaf(-gi, x.y, g00r * x.x)));
                s[j].y = fmaf( g01i, p1.x, fmaf(br, p1.y, fmaf( gi, x.x, g00r * x.y)));
            }
            {
                const bool n = (__builtin_popcount(j2 & UREG) & 1) != 0;
                const float gi = n ? -giP : giP, br = n ? -brP : brP;
                s[j2].x = fmaf(-g01i, p2.y, fmaf(br, p2.x, fmaf(-gi, y.y, g00r * y.x)));
                s[j2].y = fmaf( g01i, p2.x, fmaf(br, p2.y, fmaf( gi, y.x, g00r * y.y)));
            }
        }
    }
}

#define ROT0(K, VR, VL, UR, SL) do {                                       \
    const float4 g_ = *reinterpret_cast<const float4*>(&gbuf[(K)*4]);      \
    gateU<VR, VL, UR>(s, g_.x, uxor(g_.y, SL), uxor(g_.z, SL), g_.w);      \
} while (0)

// fused: F = Rot(1,K) . Renc(K); only F00,F01 needed (SU(2))
#define FUSED(K, VR, VL, UR, SL) do {                                      \
    const float4 g_ = *reinterpret_cast<const float4*>(&gbuf[(8+(K))*4]);  \
    const f2 R00 = {g_.x, g_.y}, R01 = {g_.z, g_.w};                       \
    float c_, s_, cp_, sp_;                                                \
    __sincosf(th[K] * 0.25f, &s_, &c_);                                    \
    __sincosf(ph[K] * 0.25f, &sp_, &cp_);                                  \
    const f2 E00 = { c_*cp_, -c_*sp_}, E10 = { s_*cp_,  s_*sp_};           \
    const f2 E01 = {-s_*cp_,  s_*sp_}, E11 = { c_*cp_,  c_*sp_};           \
    const f2 F00 = cmadd(cmul2(R00, E00), R01, E10);                       \
    const f2 F01 = cmadd(cmul2(R00, E01), R01, E11);                       \
    gateU<VR, VL, UR>(s, F00.x, uxor(F00.y, SL), uxor(F01.x, SL), F01.y);  \
} while (0)

__global__ __launch_bounds__(256, 4) void vqc_kernel(
    const float* __restrict__ theta,   // [B,8]
    const float* __restrict__ phi,     // [B,8]
    const float* __restrict__ jup,     // [B,28]
    const float* __restrict__ w,       // [2,8,3]
    float* __restrict__ out,           // [B,8]
    int Btot)
{
    const int t      = threadIdx.x;
    const int lane32 = t & 31;
    const int bq     = blockIdx.x * 8 + (t >> 5);
    const int b      = bq < Btot ? bq : Btot - 1;

    // ---- per-block gate-matrix precompute (lanes 0..15), LDS broadcast ----
    // Rot = RZ(om)RY(th)RZ(ph): g00=c e^{-i(ph+om)/2}, g01=-s e^{+i(ph-om)/2}
    __shared__ float gbuf[64];
    if (t < 16) {
        const float wph = w[t*3+0], wth = w[t*3+1], wom = w[t*3+2];
        float c_, s_, ca_, sa_, cb_, sb_;
        __sincosf(wth * 0.5f, &s_, &c_);
        __sincosf(0.5f * (wph + wom), &sa_, &ca_);
        __sincosf(0.5f * (wph - wom), &sb_, &cb_);
        gbuf[t*4+0] =  c_*ca_;  gbuf[t*4+1] = -c_*sa_;   // g00
        gbuf[t*4+2] = -s_*cb_;  gbuf[t*4+3] = -s_*sb_;   // g01
    }
    __syncthreads();

    float th[8], ph[8];
    {
        const float4* t4 = reinterpret_cast<const float4*>(theta + (size_t)b * 8);
        const float4* p4 = reinterpret_cast<const float4*>(phi   + (size_t)b * 8);
        const float4 a = t4[0], c = t4[1], d = p4[0], e = p4[1];
        th[0]=a.x; th[1]=a.y; th[2]=a.z; th[3]=a.w;
        th[4]=c.x; th[5]=c.y; th[6]=c.z; th[7]=c.w;
        ph[0]=d.x; ph[1]=d.y; ph[2]=d.z; ph[3]=d.w;
        ph[4]=e.x; ph[5]=e.y; ph[6]=e.z; ph[7]=e.w;
    }

    // lane-parity sign words (bit31) for ULANE masks
    const unsigned s16 = (unsigned)(lane32 & 16) << 27;
    const unsigned s8  = (unsigned)(lane32 &  8) << 28;
    const unsigned s4  = (unsigned)(lane32 &  4) << 29;
    const unsigned s2  = (unsigned)(lane32 &  2) << 30;
    const unsigned s1  = (unsigned)(lane32 &  1) << 31;
    const unsigned s18 = s16 ^ s8;
    const unsigned s1C = s18 ^ s4;
    const unsigned s1E = s1C ^ s2;
    const unsigned s1F = s1E ^ s1;

    // ---- lane-side encoding product over qubits 3..7 (lane bits 4..0) ----
    f2 P = enc_sel(th[3], ph[3], (lane32 & 16) != 0);
    P = cmul2(P, enc_sel(th[4], ph[4], (lane32 & 8) != 0));
    P = cmul2(P, enc_sel(th[5], ph[5], (lane32 & 4) != 0));
    P = cmul2(P, enc_sel(th[6], ph[6], (lane32 & 2) != 0));
    P = cmul2(P, enc_sel(th[7], ph[7], (lane32 & 1) != 0));

    // ---- register-side: m01 over (q0,q1) [j bits 2,1], e2 entries for q2 ----
    f2 m01[4], e20, e21;
    {
        float s0, c0, sp0, cp0, s1_, c1_, sp1, cp1;
        __sincosf(th[0]*0.5f, &s0, &c0); __sincosf(ph[0]*0.5f, &sp0, &cp0);
        __sincosf(th[1]*0.5f, &s1_, &c1_); __sincosf(ph[1]*0.5f, &sp1, &cp1);
        const f2 A0={c0*cp0,-c0*sp0}, A1={s0*cp0,s0*sp0};
        const f2 B0={c1_*cp1,-c1_*sp1}, B1={s1_*cp1,s1_*sp1};
        #pragma unroll
        for (int a = 0; a < 4; ++a)
            m01[a] = cmul2((a & 2) ? A1 : A0, (a & 1) ? B1 : B0);
        __sincosf(th[2]*0.5f, &s0, &c0); __sincosf(ph[2]*0.5f, &sp0, &cp0);
        e20 = (f2){c0*cp0, -c0*sp0};
        e21 = (f2){s0*cp0,  s0*sp0};
    }

    // ---- IsingZZ reduction: J[28] -> c01,c02,c12, Q0..Q2 (5-term), LL ----
    // pair order (i<j lex): (0,1)(0,2)(0,3..7)(1,2)(1,3..7)(2,3..7)(3,4..7)...
    float c01, c02, c12, Q0, Q1, Q2, LL;
    {
        const float4* J4 = reinterpret_cast<const float4*>(jup + (size_t)b * 28);
        const float z3 = (lane32 & 16) ? -1.f : 1.f;
        const float z4 = (lane32 &  8) ? -1.f : 1.f;
        const float z5 = (lane32 &  4) ? -1.f : 1.f;
        const float z6 = (lane32 &  2) ? -1.f : 1.f;
        const float z7 = (lane32 &  1) ? -1.f : 1.f;
        const float4 x0 = J4[0], x1 = J4[1], x2 = J4[2], x3 = J4[3];
        const float4 x4 = J4[4], x5 = J4[5], x6 = J4[6];
        // J: x0={J0,J1,J2,J3} x1={J4..J7} x2={J8..J11} x3={J12..J15}
        //    x4={J16..J19} x5={J20..J23} x6={J24..J27}
        c01 = x0.x; c02 = x0.y; c12 = x1.w;
        Q0 = x0.z*z3 + x0.w*z4 + x1.x*z5 + x1.y*z6 + x1.z*z7;   // J2..J6
        Q1 = x2.x*z3 + x2.y*z4 + x2.z*z5 + x2.w*z6 + x3.x*z7;   // J8..J12
        Q2 = x3.y*z3 + x3.z*z4 + x3.w*z5 + x4.x*z6 + x4.y*z7;   // J13..J17
        LL = x4.z*(z3*z4) + x4.w*(z3*z5) + x5.x*(z3*z6) + x5.y*(z3*z7)  // J18..21
           + x5.z*(z4*z5) + x5.w*(z4*z6) + x6.x*(z4*z7)                 // J22..24
           + x6.y*(z5*z6) + x6.z*(z5*z7) + x6.w*(z6*z7);                // J25..27
    }

    // ---- init amplitudes: product state x Ising phase (8 amps) ----
    f2 s[8];
    constexpr float HPI = 1.5707963267948966f;
    #pragma unroll
    for (int j = 0; j < 8; ++j) {
        f2 u = cmul2(cmul2(m01[j >> 1], (j & 1) ? e21 : e20), P);
        float S = LL;
        S += ((__builtin_popcount(j & 6) & 1) ? -c01 : c01);
        S += ((__builtin_popcount(j & 5) & 1) ? -c02 : c02);
        S += ((__builtin_popcount(j & 3) & 1) ? -c12 : c12);
        S += ((j & 4) ? -Q0 : Q0);
        S += ((j & 2) ? -Q1 : Q1);
        S += ((j & 1) ? -Q2 : Q2);
        float se, ce;
        __sincosf(-HPI * S, &se, &ce);
        s[j] = cmul2(u, (f2){ce, se});
    }

    // ---- layer-0 Rot gates (A = I): v = u = e_p, p = 7-k ----
    ROT0(0, 0x4, 0x00, 0x4, 0u);
    ROT0(1, 0x2, 0x00, 0x2, 0u);
    ROT0(2, 0x1, 0x00, 0x1, 0u);
    ROT0(3, 0x0, 0x10, 0x0, s16);
    ROT0(4, 0x0, 0x08, 0x0, s8);
    ROT0(5, 0x0, 0x04, 0x0, s4);
    ROT0(6, 0x0, 0x02, 0x0, s2);
    ROT0(7, 0x0, 0x01, 0x0, s1);

    // ---- layer-0 CNOT ring folded; RENC+ROT(1,k) fused (v/u re-split 3|5) ----
    FUSED(0, 0x6, 0x00, 0x3, s1F);   // v8=0xC0 u8=0x7F
    FUSED(1, 0x3, 0x00, 0x6, 0u);    // v8=0x60 u8=0xC0
    FUSED(2, 0x1, 0x10, 0x7, 0u);    // v8=0x30 u8=0xE0
    FUSED(3, 0x0, 0x18, 0x7, s16);   // v8=0x18 u8=0xF0
    FUSED(4, 0x0, 0x0C, 0x7, s18);   // v8=0x0C u8=0xF8
    FUSED(5, 0x0, 0x06, 0x7, s1C);   // v8=0x06 u8=0xFC
    FUSED(6, 0x0, 0x03, 0x7, s1E);   // v8=0x03 u8=0xFE
    FUSED(7, 0x6, 0x01, 0x7, s1F);   // v8=0xC1 u8=0xFF

    // ---- readout: probs, 8-point WHT over j, lane signs (final A rows) ----
    float p[8];
    #pragma unroll
    for (int j = 0; j < 8; ++j) p[j] = fmaf(s[j].y, s[j].y, s[j].x * s[j].x);
    #pragma unroll
    for (int st = 1; st < 8; st <<= 1) {
        #pragma unroll
        for (int j = 0; j < 8; ++j) {
            if ((j & st) != 0) continue;
            const float a = p[j], bb = p[j | st];
            p[j] = a + bb;  p[j | st] = a - bb;
        }
    }
    // rows: k0:0xE6 k1:0xF3 k2:0x9F k3:0x30 k4:0x67 k5:0xCC k6:0x99 k7:0x33
    const unsigned s06 = s4 ^ s2;
    const unsigned s13 = s16 ^ s2 ^ s1;
    const unsigned s07 = s06 ^ s1;
    const unsigned s0C = s8 ^ s4;
    const unsigned s19 = s18 ^ s1;
    float o0 = uxor(p[7], s06);
    float o1 = uxor(p[7], s13);
    float o2 = uxor(p[4], s1F);
    float o3 = uxor(p[1], s16);
    float o4 = uxor(p[3], s07);
    float o5 = uxor(p[6], s0C);
    float o6 = uxor(p[4], s19);
    float o7 = uxor(p[1], s13);

    #define REDSTEP(M) do { o0 += swzf<M>(o0); o1 += swzf<M>(o1);      \
        o2 += swzf<M>(o2); o3 += swzf<M>(o3); o4 += swzf<M>(o4);       \
        o5 += swzf<M>(o5); o6 += swzf<M>(o6); o7 += swzf<M>(o7); } while (0)
    REDSTEP(1); REDSTEP(2); REDSTEP(4); REDSTEP(8); REDSTEP(16);
    #undef REDSTEP

    if (lane32 == 0 && bq < Btot) {
        float4* op = reinterpret_cast<float4*>(out + (size_t)bq * 8);
        op[0] = make_float4(o0, o1, o2, o3);
        op[1] = make_float4(o4, o5, o6, o7);
    }
}

extern "C" void kernel_launch(void* const* d_in, const int* in_sizes, int n_in,
                              void* d_out, int out_size, void* d_ws, size_t ws_size,
                              hipStream_t stream) {
    const float* theta = (const float*)d_in[0];
    const float* phi   = (const float*)d_in[1];
    const float* jup   = (const float*)d_in[2];
    const float* w     = (const float*)d_in[3];
    float* out = (float*)d_out;

    const int B = in_sizes[0] / 8;               // 16384
    const int blocks = (B + 7) / 8;              // 2048: 8 batch elems / block
    hipLaunchKernelGGL(vqc_kernel, dim3(blocks), dim3(256), 0, stream,
                       theta, phi, jup, w, out, B);
}